// Round 3
// baseline (125.020 us; speedup 1.0000x reference)
//
#include <hip/hip_runtime.h>
#include <stdint.h>

#define NS 65536      // B*H*W samples
#define D 64          // embed dim
#define K 1024        // codebook size
#define NEL 4194304   // NS*D
#define MARGIN_KEY 0.025f  // key units = half dist units (old 0.05 dist margin)

typedef short bf16x8 __attribute__((ext_vector_type(8)));
typedef short s16x4 __attribute__((ext_vector_type(4)));
typedef float f32x4 __attribute__((ext_vector_type(4)));

static __device__ __forceinline__ unsigned short bf16_rne(float x) {
    union { float f; uint32_t u; } v; v.f = x;
    uint32_t r = v.u + 0x7FFFu + ((v.u >> 16) & 1u);
    return (unsigned short)(r >> 16);
}
static __device__ __forceinline__ float bf16f(unsigned short h) {
    union { uint32_t u; float f; } v; v.u = ((uint32_t)h) << 16;
    return v.f;
}

// ---------------------------------------------------------------------------
// Prep: split codebook into bf16 hi/lo and pack in MFMA-FRAGMENT order:
//   P[tile t][frag f][lane l][8 shorts],  t=k>>4, f: 0=hi d0-31, 1=hi d32-63,
//   2=lo d0-31, 3=lo d32-63; lane = ((d&31)>>3)*16 + (k&15), elem = d&7.
// vq_main's per-tile B loads are 64-lane contiguous 1 KB reads.
// Also computes ||m_k||^2 fp32 and zeroes the loss accumulator.
// ---------------------------------------------------------------------------
__global__ __launch_bounds__(256) void vq_prep(
    const float* __restrict__ cm,        // [D,K]
    unsigned short* __restrict__ P,      // packed frags, 256 KB
    float* __restrict__ cnorm,           // [K]
    double* __restrict__ acc)
{
    const int tx = threadIdx.x;
    const int col = tx & 15;             // code within block's 16
    const int dg = tx >> 4;              // dim group 0..15 (4 dims each)
    const int b = blockIdx.x;            // == tile index t
    const int k = b * 16 + col;
    if (b == 0 && tx == 0) *acc = 0.0;

    float p = 0.f;
    s16x4 hv, lv;
#pragma unroll
    for (int j = 0; j < 4; ++j) {
        float v = cm[(dg * 4 + j) * K + k];   // 16 consecutive floats / 16 lanes
        unsigned short hb = bf16_rne(v);
        hv[j] = (short)hb;
        lv[j] = (short)bf16_rne(v - bf16f(hb));
        p = fmaf(v, v, p);
    }
    // dims dg*4..+4 live in frag (dg>>3), lane ((dg>>1)&3)*16+col, elem (dg&1)*4
    const int lane = ((dg >> 1) & 3) * 16 + col;
    const int e0 = (dg & 1) * 4;
    unsigned short* ph = P + ((size_t)(b * 4 + (dg >> 3)) * 64 + lane) * 8 + e0;
    unsigned short* pl = P + ((size_t)(b * 4 + 2 + (dg >> 3)) * 64 + lane) * 8 + e0;
    *(s16x4*)ph = hv;
    *(s16x4*)pl = lv;

    __shared__ float pn[16][17];
    pn[col][dg] = p;
    __syncthreads();
    if (tx < 16) {
        float s = 0.f;
#pragma unroll
        for (int g = 0; g < 16; ++g) s += pn[tx][g];
        cnorm[b * 16 + tx] = s;
    }
}

// ---------------------------------------------------------------------------
// Main: barrier-free MFMA distance loop, 32 SAMPLES PER WAVE (halves the
// per-work B cache traffic that co-limited round 2: each wave privately
// streams the 256 KB packed codebook; 4 MB/CU at 16 samples/wave -> 2 MB/CU
// at 32). 512 blocks x 256 thr (4 waves); wave w owns samples w*32..+32 as
// two 16-row A-tile groups (two independent 6-MFMA chains -> ILP).
// x is staged NEGATED so MFMA C-in = ||m||^2/2 yields key = cn/2 - dot
// directly (dist = ||x||^2 + 2*key); track MIN key, exact top-2 + indices,
// margin cases rescored exactly in fp32 from original cm.
// ---------------------------------------------------------------------------
__global__ __launch_bounds__(256, 2) void vq_main(
    const float* __restrict__ xin,           // [NS,D]
    const float* __restrict__ cm,            // [D,K] (exact rescore)
    const unsigned short* __restrict__ P,    // packed frags
    const float* __restrict__ cnorm,         // [K]
    float* __restrict__ outq,                // [NS,D]
    float* __restrict__ outidx,              // [NS]
    double* __restrict__ acc_g)
{
    // smemA phase1: xh[128][72] + xl[128][72] (36864 B), -x bf16 hi/lo
    // smemA phase2 (alias): skewed mb1/mb2 f32 + mi1/mi2 i32 (4 x 8704 B)
    // smemA phase3 (alias): red f32[256]
    __shared__ char smemA[36864];
    __shared__ float cn_lds[1024];     // ||m||^2 / 2
    __shared__ int   widx[128];

    unsigned short* xh = (unsigned short*)smemA;            // stride 72
    unsigned short* xl = (unsigned short*)(smemA + 18432);
    float* mb1 = (float*)smemA;
    float* mb2 = (float*)(smemA + 8704);
    int*   mi1 = (int*)(smemA + 17408);
    int*   mi2 = (int*)(smemA + 26112);
    float* red = (float*)smemA;

    const int tx = threadIdx.x;
    const int S0 = blockIdx.x * 128;
    const int w = tx >> 6, l = tx & 63;
    const int quad = l >> 4, col = l & 15;

    // B fragment base: tile t, frag f, lane l at P + (t*4+f)*512 + l*8 shorts
    const unsigned short* pb = P + (size_t)l * 8;

#define LDB(B0, B1, B2, B3, T) do {                                   \
        const unsigned short* q_ = pb + (size_t)(T) * 2048;           \
        B0 = *(const bf16x8*)(q_);                                    \
        B1 = *(const bf16x8*)(q_ + 512);                              \
        B2 = *(const bf16x8*)(q_ + 1024);                             \
        B3 = *(const bf16x8*)(q_ + 1536);                             \
    } while (0)

    // issue tile 0/1 B loads immediately (overlap with x staging below)
    bf16x8 c0, c1, c2, c3, n0, n1, n2, n3;
    LDB(c0, c1, c2, c3, 0);
    LDB(n0, n1, n2, n3, 1);

    // ---- stage -x -> bf16 hi/lo in LDS (one-time, one barrier) ----
    {
        const int s = tx >> 2, d0 = (tx & 3) * 16;
#pragma unroll
        for (int half = 0; half < 2; ++half) {
            const int ss = s + half * 64;
            const float* gp = xin + (size_t)(S0 + ss) * D + d0;
            bf16x8 hv0, hv1, lv0, lv1;
#pragma unroll
            for (int j = 0; j < 8; ++j) {
                float va = -gp[j], vb = -gp[8 + j];
                unsigned short ha = bf16_rne(va), hb = bf16_rne(vb);
                hv0[j] = (short)ha; hv1[j] = (short)hb;
                lv0[j] = (short)bf16_rne(va - bf16f(ha));
                lv1[j] = (short)bf16_rne(vb - bf16f(hb));
            }
            *(bf16x8*)(xh + ss * 72 + d0)     = hv0;
            *(bf16x8*)(xh + ss * 72 + d0 + 8) = hv1;
            *(bf16x8*)(xl + ss * 72 + d0)     = lv0;
            *(bf16x8*)(xl + ss * 72 + d0 + 8) = lv1;
        }
#pragma unroll
        for (int q = 0; q < 4; ++q)
            cn_lds[q * 256 + tx] = 0.5f * cnorm[q * 256 + tx];
    }
    __syncthreads();

    // loop-invariant A fragments (-x): sample group sg rows w*32+sg*16+...,
    // this lane's A row = w*32 + sg*16 + col, dims quad*8 (+32)
    bf16x8 AH0[2], AH1[2], AL0[2], AL1[2];
#pragma unroll
    for (int sg = 0; sg < 2; ++sg) {
        const int srow = w * 32 + sg * 16 + col;
        AH0[sg] = *(const bf16x8*)(xh + srow * 72 + quad * 8);
        AH1[sg] = *(const bf16x8*)(xh + srow * 72 + 32 + quad * 8);
        AL0[sg] = *(const bf16x8*)(xl + srow * 72 + quad * 8);
        AL1[sg] = *(const bf16x8*)(xl + srow * 72 + 32 + quad * 8);
    }

    // track MIN of key = cn/2 - dot  (dist = ||x||^2 + 2*key)
    float b1[2][4], b2[2][4]; int i1[2][4], i2[2][4];
#pragma unroll
    for (int sg = 0; sg < 2; ++sg)
#pragma unroll
        for (int r = 0; r < 4; ++r) {
            b1[sg][r] = 3.4e38f; b2[sg][r] = 3.4e38f;
            i1[sg][r] = 0; i2[sg][r] = 0;
        }

#define COMPUTE(B0, B1, B2, B3, T) do {                                        \
        const int kc_ = (T) * 16 + col;                                        \
        const float cv_ = cn_lds[kc_];                                         \
        const f32x4 cc_ = {cv_, cv_, cv_, cv_};                                \
        _Pragma("unroll")                                                      \
        for (int sg = 0; sg < 2; ++sg) {                                       \
            f32x4 a_ = cc_;                                                    \
            a_ = __builtin_amdgcn_mfma_f32_16x16x32_bf16(AH0[sg], B0, a_, 0, 0, 0); \
            a_ = __builtin_amdgcn_mfma_f32_16x16x32_bf16(AH1[sg], B1, a_, 0, 0, 0); \
            a_ = __builtin_amdgcn_mfma_f32_16x16x32_bf16(AH0[sg], B2, a_, 0, 0, 0); \
            a_ = __builtin_amdgcn_mfma_f32_16x16x32_bf16(AH1[sg], B3, a_, 0, 0, 0); \
            a_ = __builtin_amdgcn_mfma_f32_16x16x32_bf16(AL0[sg], B0, a_, 0, 0, 0); \
            a_ = __builtin_amdgcn_mfma_f32_16x16x32_bf16(AL1[sg], B1, a_, 0, 0, 0); \
            _Pragma("unroll")                                                  \
            for (int r = 0; r < 4; ++r) {                                      \
                float v_ = a_[r];                                              \
                bool c1_ = v_ < b1[sg][r];                                     \
                bool c2_ = v_ < b2[sg][r];                                     \
                b2[sg][r] = __builtin_amdgcn_fmed3f(b1[sg][r], v_, b2[sg][r]); \
                b1[sg][r] = fminf(b1[sg][r], v_);                              \
                i2[sg][r] = c1_ ? i1[sg][r] : (c2_ ? kc_ : i2[sg][r]);         \
                i1[sg][r] = c1_ ? kc_ : i1[sg][r];                             \
            }                                                                  \
        }                                                                      \
    } while (0)

    for (int t = 0; t < 64; t += 2) {
        COMPUTE(c0, c1, c2, c3, t);
        if (t + 2 < 64) LDB(c0, c1, c2, c3, t + 2);
        COMPUTE(n0, n1, n2, n3, t + 1);
        if (t + 3 < 64) LDB(n0, n1, n2, n3, t + 3);
    }

    // ---- merge per-lane top-2 across the 16 code-lanes ----
    __syncthreads();   // all waves done with xh/xl alias region
#pragma unroll
    for (int sg = 0; sg < 2; ++sg) {
        const int u = (w * 2 + sg) * 64 + l;
        const int sk = 4 * (u + (u >> 4));
#pragma unroll
        for (int r = 0; r < 4; ++r) {
            mb1[sk + r] = b1[sg][r];
            mb2[sk + r] = b2[sg][r];
            mi1[sk + r] = i1[sg][r];
            mi2[sk + r] = i2[sg][r];
        }
    }
    __syncthreads();

    if (tx < 128) {   // thread tx owns local sample tx
        const int mw = tx >> 5, msg = (tx >> 4) & 1, mq = (tx >> 2) & 3, mr = tx & 3;
        float B1 = 3.4e38f, B2 = 3.4e38f; int I1 = 0, I2 = 0;
#pragma unroll
        for (int c = 0; c < 16; ++c) {
            const int u = (mw * 2 + msg) * 64 + mq * 16 + c;
            const int e = 4 * (u + (u >> 4)) + mr;
            float v1 = mb1[e]; int j1 = mi1[e];
            float v2 = mb2[e]; int j2 = mi2[e];
            if (v1 < B1)      { B2 = B1; I2 = I1; B1 = v1; I1 = j1; }
            else if (v1 < B2) { B2 = v1; I2 = j1; }
            if (v2 < B1)      { B2 = B1; I2 = I1; B1 = v2; I1 = j2; }
            else if (v2 < B2) { B2 = v2; I2 = j2; }
        }
        int winner = I1;
        if (B2 - B1 < MARGIN_KEY) {
            // exact fp32 rescore of both candidates (key = cn/2 - dot)
            const float* xp = xin + (size_t)(S0 + tx) * D;
            float a0 = 0, a1 = 0, a2 = 0, a3 = 0, e0 = 0, e1 = 0, e2 = 0, e3 = 0;
            for (int dd = 0; dd < D; dd += 4) {
                float x0 = xp[dd], x1 = xp[dd + 1], x2 = xp[dd + 2], x3 = xp[dd + 3];
                a0 = fmaf(x0, cm[(dd + 0) * K + I1], a0);
                a1 = fmaf(x1, cm[(dd + 1) * K + I1], a1);
                a2 = fmaf(x2, cm[(dd + 2) * K + I1], a2);
                a3 = fmaf(x3, cm[(dd + 3) * K + I1], a3);
                e0 = fmaf(x0, cm[(dd + 0) * K + I2], e0);
                e1 = fmaf(x1, cm[(dd + 1) * K + I2], e1);
                e2 = fmaf(x2, cm[(dd + 2) * K + I2], e2);
                e3 = fmaf(x3, cm[(dd + 3) * K + I2], e3);
            }
            float d1 = cn_lds[I1] - ((a0 + a1) + (a2 + a3));
            float d2 = cn_lds[I2] - ((e0 + e1) + (e2 + e3));
            if (d2 < d1 || (d2 == d1 && I2 < I1)) winner = I2;
        }
        widx[tx] = winner;
    }
    __syncthreads();

    // ---- gather (hi+lo reconstruct from packed P) + STE + loss partial ----
    float psum = 0.f;
#pragma unroll
    for (int half = 0; half < 2; ++half) {
        const int sl = (tx >> 2) + half * 64, d0 = (tx & 3) * 16;
        const int gs = S0 + sl;
        const int wi = widx[sl];
        const int gt = wi >> 4, gc = wi & 15;
        const int qq = (d0 >> 3) & 3;        // 0 or 2
        const int gf = d0 >> 5;              // 0 or 1
        const unsigned short* gh = P + ((size_t)((gt * 4 + gf) * 64) + qq * 16 + gc) * 8;
        const unsigned short* gl = P + ((size_t)((gt * 4 + 2 + gf) * 64) + qq * 16 + gc) * 8;
        bf16x8 h0 = *(const bf16x8*)(gh);          // dims d0..d0+8
        bf16x8 h1 = *(const bf16x8*)(gh + 128);    // dims d0+8..d0+16
        bf16x8 l0 = *(const bf16x8*)(gl);
        bf16x8 l1 = *(const bf16x8*)(gl + 128);
        const float* xr = xin + (size_t)gs * D + d0;
        float* oq = outq + (size_t)gs * D + d0;
#pragma unroll
        for (int g = 0; g < 4; ++g) {
            float4 xv = *(const float4*)(xr + 4 * g);
            float q0 = bf16f((unsigned short)(g < 2 ? h0[4 * g + 0] : h1[4 * g - 8 + 0])) +
                       bf16f((unsigned short)(g < 2 ? l0[4 * g + 0] : l1[4 * g - 8 + 0]));
            float q1 = bf16f((unsigned short)(g < 2 ? h0[4 * g + 1] : h1[4 * g - 8 + 1])) +
                       bf16f((unsigned short)(g < 2 ? l0[4 * g + 1] : l1[4 * g - 8 + 1]));
            float q2 = bf16f((unsigned short)(g < 2 ? h0[4 * g + 2] : h1[4 * g - 8 + 2])) +
                       bf16f((unsigned short)(g < 2 ? l0[4 * g + 2] : l1[4 * g - 8 + 2]));
            float q3 = bf16f((unsigned short)(g < 2 ? h0[4 * g + 3] : h1[4 * g - 8 + 3])) +
                       bf16f((unsigned short)(g < 2 ? l0[4 * g + 3] : l1[4 * g - 8 + 3]));
            float dx = q0 - xv.x, dy = q1 - xv.y, dz = q2 - xv.z, dw = q3 - xv.w;
            float4 o;
            o.x = xv.x + dx; o.y = xv.y + dy; o.z = xv.z + dz; o.w = xv.w + dw;
            *(float4*)(oq + 4 * g) = o;
            psum = fmaf(dx, dx, psum);
            psum = fmaf(dy, dy, psum);
            psum = fmaf(dz, dz, psum);
            psum = fmaf(dw, dw, psum);
        }
    }

    if (tx < 128)
        outidx[S0 + tx] = (float)widx[tx];

    __syncthreads();   // merge arrays dead; red aliases
    red[tx] = psum;
    __syncthreads();
    for (int st = 128; st > 0; st >>= 1) {
        if (tx < st) red[tx] += red[tx + st];
        __syncthreads();
    }
    if (tx == 0) atomicAdd(acc_g, (double)red[0]);
#undef LDB
#undef COMPUTE
}

// ---------------------------------------------------------------------------
// Finalize: loss = m + 0.25*m where m = mean((q-x)^2)
// ---------------------------------------------------------------------------
__global__ void vq_finalize(const double* __restrict__ acc,
                            float* __restrict__ loss_out)
{
    float m = (float)(*acc / (double)NEL);
    *loss_out = m + 0.25f * m;
}

extern "C" void kernel_launch(void* const* d_in, const int* in_sizes, int n_in,
                              void* d_out, int out_size, void* d_ws, size_t ws_size,
                              hipStream_t stream) {
    const float* xin = (const float*)d_in[0];   // [16,64,64,64] fp32
    const float* cm  = (const float*)d_in[1];   // [64,1024] fp32

    float* out     = (float*)d_out;
    float* outq    = out;                 // 4194304 floats
    float* outidx  = out + NEL;           // 65536 floats (indices)
    float* outloss = out + NEL + NS;      // 1 float

    // workspace: packed P 256 KB | cnorm 4 KB | acc 8 B
    unsigned short* P = (unsigned short*)d_ws;
    float*  cnorm = (float*)((char*)d_ws + 262144);
    double* acc   = (double*)((char*)d_ws + 266240);

    vq_prep<<<64, 256, 0, stream>>>(cm, P, cnorm, acc);
    vq_main<<<512, 256, 0, stream>>>(xin, cm, P, cnorm, outq, outidx, acc);
    vq_finalize<<<1, 1, 0, stream>>>(acc, outloss);
}

// Round 4
// 123.135 us; speedup vs baseline: 1.0153x; 1.0153x over previous
//
#include <hip/hip_runtime.h>
#include <stdint.h>

#define NS 65536      // B*H*W samples
#define D 64          // embed dim
#define K 1024        // codebook size
#define NEL 4194304   // NS*D
#define MARGIN_KEY 0.025f  // key units (= half dist units); covers 2.7e-3 approx+pack err

typedef short bf16x8 __attribute__((ext_vector_type(8)));
typedef short s16x4 __attribute__((ext_vector_type(4)));
typedef float f32x4 __attribute__((ext_vector_type(4)));

static __device__ __forceinline__ unsigned short bf16_rne(float x) {
    union { float f; uint32_t u; } v; v.f = x;
    uint32_t r = v.u + 0x7FFFu + ((v.u >> 16) & 1u);
    return (unsigned short)(r >> 16);
}
static __device__ __forceinline__ float bf16f(unsigned short h) {
    union { uint32_t u; float f; } v; v.u = ((uint32_t)h) << 16;
    return v.f;
}

// ---------------------------------------------------------------------------
// Prep: split codebook into bf16 hi/lo, packed in MFMA-fragment order:
//   P[tile t][frag f][lane l][8 shorts]; f: 0=hi d0-31, 1=hi d32-63,
//   2=lo d0-31, 3=lo d32-63; lane = ((d&31)>>3)*16 + (k&15).
// Per-tile = 4 KB contiguous -> both global_load_lds staging and ds_read
// consumption are perfectly linear. Also ||m_k||^2 fp32 + acc zero.
// ---------------------------------------------------------------------------
__global__ __launch_bounds__(256) void vq_prep(
    const float* __restrict__ cm,        // [D,K]
    unsigned short* __restrict__ P,      // packed frags, 256 KB
    float* __restrict__ cnorm,           // [K]
    double* __restrict__ acc)
{
    const int tx = threadIdx.x;
    const int col = tx & 15;             // code within block's 16
    const int dg = tx >> 4;              // dim group 0..15 (4 dims each)
    const int b = blockIdx.x;            // == tile index t
    const int k = b * 16 + col;
    if (b == 0 && tx == 0) *acc = 0.0;

    float p = 0.f;
    s16x4 hv, lv;
#pragma unroll
    for (int j = 0; j < 4; ++j) {
        float v = cm[(dg * 4 + j) * K + k];   // 16 consecutive floats / 16 lanes
        unsigned short hb = bf16_rne(v);
        hv[j] = (short)hb;
        lv[j] = (short)bf16_rne(v - bf16f(hb));
        p = fmaf(v, v, p);
    }
    const int lane = ((dg >> 1) & 3) * 16 + col;
    const int e0 = (dg & 1) * 4;
    unsigned short* ph = P + ((size_t)(b * 4 + (dg >> 3)) * 64 + lane) * 8 + e0;
    unsigned short* pl = P + ((size_t)(b * 4 + 2 + (dg >> 3)) * 64 + lane) * 8 + e0;
    *(s16x4*)ph = hv;
    *(s16x4*)pl = lv;

    __shared__ float pn[16][17];
    pn[col][dg] = p;
    __syncthreads();
    if (tx < 16) {
        float s = 0.f;
#pragma unroll
        for (int g = 0; g < 16; ++g) s += pn[tx][g];
        cnorm[b * 16 + tx] = s;
    }
}

// ---------------------------------------------------------------------------
// Main: LDS-shared B + counted-vmcnt pipeline (T3/T4 pattern).
// 512 blocks x 256 thr (4 waves); block owns 128 samples, wave w owns 32
// (2 groups of 16). B tiles (4 KB) staged into a 4-deep LDS ring via
// global_load_lds (each thread 16 B), prefetch distance 3. Per tile:
//   s_waitcnt vmcnt(2)  -> own share of tile t landed
//   s_barrier (raw)     -> ALL waves' shares landed (no vmcnt(0) drain!)
//   issue tile t+3      -> overwrites buf[(t-1)&3], whose reads were
//                          register-consumed before this barrier (safe)
//   ds_read frags + 12 MFMA (two 3-chains/group for ILP) + top-2
// This is round-0's traffic (256 KB L2 per BLOCK, not per wave) without
// round-0's 128 vmcnt(0) barrier drains (the m97-ceiling mechanism).
// Top-2 keys carry the tile index in their low 6 mantissa bits (pack err
// <= 2e-3 << margin), so the update is and/or+med3+min -- no index cndmasks.
// x staged NEGATED: key = ||m||^2/2 - x.m directly from MFMA (C-in = cn/2).
// ---------------------------------------------------------------------------
__global__ __launch_bounds__(256, 2) void vq_main(
    const float* __restrict__ xin,           // [NS,D]
    const float* __restrict__ cm,            // [D,K] (exact rescore)
    const unsigned short* __restrict__ P,    // packed frags
    const float* __restrict__ cnorm,         // [K]
    float* __restrict__ outq,                // [NS,D]
    float* __restrict__ outidx,              // [NS]
    double* __restrict__ acc_g)
{
    // smemA phase1: xh[128][72] + xl[128][72] (36864 B), -x bf16 hi/lo
    // smemA phase2 (alias): skewed packed mb1/mb2 (2 x ~8.7 KB)
    // smemA phase3 (alias): red f32[256]
    __shared__ char smemA[36864];
    __shared__ unsigned short btile[4][2048];   // 4-deep ring of 4 KB B tiles
    __shared__ float cn_lds[1024];              // ||m||^2 / 2
    __shared__ int   widx[128];

    unsigned short* xh = (unsigned short*)smemA;            // stride 72
    unsigned short* xl = (unsigned short*)(smemA + 18432);
    float* mb1 = (float*)smemA;
    float* mb2 = (float*)(smemA + 8704);
    float* red = (float*)smemA;

    const int tx = threadIdx.x;
    const int S0 = blockIdx.x * 128;
    const int w = tx >> 6, l = tx & 63;
    const int quad = l >> 4, col = l & 15;

#define ISSUE(T) do {                                                          \
        const unsigned short* g_ = P + (size_t)(T) * 2048 + tx * 8;            \
        __builtin_amdgcn_global_load_lds(g_, &btile[(T) & 3][tx * 8], 16, 0, 0); \
    } while (0)
#define WAITV(N) asm volatile("s_waitcnt vmcnt(" #N ")" ::: "memory")

    // prologue: stage tiles 0..2 (drained by the staging __syncthreads)
    ISSUE(0); ISSUE(1); ISSUE(2);

    // ---- stage -x -> bf16 hi/lo in LDS (one-time) ----
    {
        const int s = tx >> 2, d0 = (tx & 3) * 16;
#pragma unroll
        for (int half = 0; half < 2; ++half) {
            const int ss = s + half * 64;
            const float* gp = xin + (size_t)(S0 + ss) * D + d0;
            bf16x8 hv0, hv1, lv0, lv1;
#pragma unroll
            for (int j = 0; j < 8; ++j) {
                float va = -gp[j], vb = -gp[8 + j];
                unsigned short ha = bf16_rne(va), hb = bf16_rne(vb);
                hv0[j] = (short)ha; hv1[j] = (short)hb;
                lv0[j] = (short)bf16_rne(va - bf16f(ha));
                lv1[j] = (short)bf16_rne(vb - bf16f(hb));
            }
            *(bf16x8*)(xh + ss * 72 + d0)     = hv0;
            *(bf16x8*)(xh + ss * 72 + d0 + 8) = hv1;
            *(bf16x8*)(xl + ss * 72 + d0)     = lv0;
            *(bf16x8*)(xl + ss * 72 + d0 + 8) = lv1;
        }
#pragma unroll
        for (int q = 0; q < 4; ++q)
            cn_lds[q * 256 + tx] = 0.5f * cnorm[q * 256 + tx];
    }
    __syncthreads();   // drains x writes AND tiles 0-2 (full drain, once)

    // loop-invariant A fragments (-x): row = w*32 + sg*16 + col
    bf16x8 AH0[2], AH1[2], AL0[2], AL1[2];
#pragma unroll
    for (int sg = 0; sg < 2; ++sg) {
        const int srow = w * 32 + sg * 16 + col;
        AH0[sg] = *(const bf16x8*)(xh + srow * 72 + quad * 8);
        AH1[sg] = *(const bf16x8*)(xh + srow * 72 + 32 + quad * 8);
        AL0[sg] = *(const bf16x8*)(xl + srow * 72 + quad * 8);
        AL1[sg] = *(const bf16x8*)(xl + srow * 72 + 32 + quad * 8);
    }

    // top-2 of key = cn/2 - x.m, tile idx packed in low 6 mantissa bits
    float b1[2][4], b2[2][4];
#pragma unroll
    for (int sg = 0; sg < 2; ++sg)
#pragma unroll
        for (int r = 0; r < 4; ++r) { b1[sg][r] = 3.4e38f; b2[sg][r] = 3.4e38f; }

#define BODY(T) do {                                                           \
        const unsigned short* bt_ = &btile[(T) & 3][0];                        \
        bf16x8 bh0 = *(const bf16x8*)(bt_ + l * 8);                            \
        bf16x8 bh1 = *(const bf16x8*)(bt_ + 512 + l * 8);                      \
        bf16x8 bl0 = *(const bf16x8*)(bt_ + 1024 + l * 8);                     \
        bf16x8 bl1 = *(const bf16x8*)(bt_ + 1536 + l * 8);                     \
        const float cnv_ = cn_lds[(T) * 16 + col];                             \
        const f32x4 cA_ = {cnv_, cnv_, cnv_, cnv_};                            \
        const f32x4 z4_ = {0.f, 0.f, 0.f, 0.f};                                \
        const unsigned tt_ = (unsigned)(T);                                    \
        _Pragma("unroll")                                                      \
        for (int sg = 0; sg < 2; ++sg) {                                       \
            f32x4 a1_ = __builtin_amdgcn_mfma_f32_16x16x32_bf16(AH0[sg], bh0, cA_, 0, 0, 0); \
            a1_ = __builtin_amdgcn_mfma_f32_16x16x32_bf16(AH1[sg], bh1, a1_, 0, 0, 0); \
            a1_ = __builtin_amdgcn_mfma_f32_16x16x32_bf16(AL0[sg], bh0, a1_, 0, 0, 0); \
            f32x4 a2_ = __builtin_amdgcn_mfma_f32_16x16x32_bf16(AH0[sg], bl0, z4_, 0, 0, 0); \
            a2_ = __builtin_amdgcn_mfma_f32_16x16x32_bf16(AH1[sg], bl1, a2_, 0, 0, 0); \
            a2_ = __builtin_amdgcn_mfma_f32_16x16x32_bf16(AL1[sg], bh1, a2_, 0, 0, 0); \
            _Pragma("unroll")                                                  \
            for (int r = 0; r < 4; ++r) {                                      \
                float v_ = a1_[r] + a2_[r];                                    \
                unsigned pu_ = (__builtin_bit_cast(unsigned, v_) & 0xFFFFFFC0u) | tt_; \
                float f_ = __builtin_bit_cast(float, pu_);                     \
                b2[sg][r] = __builtin_amdgcn_fmed3f(b1[sg][r], f_, b2[sg][r]); \
                b1[sg][r] = fminf(b1[sg][r], f_);                              \
            }                                                                  \
        }                                                                      \
    } while (0)

    for (int t = 0; t < 61; ++t) {
        WAITV(2);                         // own share of tile t arrived
        __builtin_amdgcn_s_barrier();     // all waves' shares arrived
        ISSUE(t + 3);                     // buf[(t-1)&3]: consumed last iter
        BODY(t);
    }
    WAITV(2); __builtin_amdgcn_s_barrier(); BODY(61);
    WAITV(1); __builtin_amdgcn_s_barrier(); BODY(62);
    WAITV(0); __builtin_amdgcn_s_barrier(); BODY(63);

    // ---- merge per-lane top-2 across the 16 code-lanes (packed values) ----
#pragma unroll
    for (int sg = 0; sg < 2; ++sg) {
        const int u = (w * 2 + sg) * 64 + l;
        const int sk = 4 * (u + (u >> 4));   // skew: ~2-way banks
#pragma unroll
        for (int r = 0; r < 4; ++r) {
            mb1[sk + r] = b1[sg][r];
            mb2[sk + r] = b2[sg][r];
        }
    }
    __syncthreads();

    if (tx < 128) {   // thread tx owns local sample tx
        const int mw = tx >> 5, msg = (tx >> 4) & 1, mq = (tx >> 2) & 3, mr = tx & 3;
        float B1 = 3.4e38f, B2 = 3.4e38f; int I1 = 0, I2 = 0;
#pragma unroll
        for (int c = 0; c < 16; ++c) {
            const int u = (mw * 2 + msg) * 64 + mq * 16 + c;
            const int e = 4 * (u + (u >> 4)) + mr;
            float v1 = mb1[e];
            float v2 = mb2[e];
            int j1 = (int)(__builtin_bit_cast(unsigned, v1) & 63u) * 16 + c;
            int j2 = (int)(__builtin_bit_cast(unsigned, v2) & 63u) * 16 + c;
            if (v1 < B1)      { B2 = B1; I2 = I1; B1 = v1; I1 = j1; }
            else if (v1 < B2) { B2 = v1; I2 = j1; }
            if (v2 < B1)      { B2 = B1; I2 = I1; B1 = v2; I1 = j2; }
            else if (v2 < B2) { B2 = v2; I2 = j2; }
        }
        int winner = I1;
        if (B2 - B1 < MARGIN_KEY) {
            // exact fp32 rescore of both candidates (key = cn/2 - dot)
            const float* xp = xin + (size_t)(S0 + tx) * D;
            float a0 = 0, a1 = 0, a2 = 0, a3 = 0, e0 = 0, e1 = 0, e2 = 0, e3 = 0;
            for (int dd = 0; dd < D; dd += 4) {
                float x0 = xp[dd], x1 = xp[dd + 1], x2 = xp[dd + 2], x3 = xp[dd + 3];
                a0 = fmaf(x0, cm[(dd + 0) * K + I1], a0);
                a1 = fmaf(x1, cm[(dd + 1) * K + I1], a1);
                a2 = fmaf(x2, cm[(dd + 2) * K + I1], a2);
                a3 = fmaf(x3, cm[(dd + 3) * K + I1], a3);
                e0 = fmaf(x0, cm[(dd + 0) * K + I2], e0);
                e1 = fmaf(x1, cm[(dd + 1) * K + I2], e1);
                e2 = fmaf(x2, cm[(dd + 2) * K + I2], e2);
                e3 = fmaf(x3, cm[(dd + 3) * K + I2], e3);
            }
            float d1 = cn_lds[I1] - ((a0 + a1) + (a2 + a3));
            float d2 = cn_lds[I2] - ((e0 + e1) + (e2 + e3));
            if (d2 < d1 || (d2 == d1 && I2 < I1)) winner = I2;
        }
        widx[tx] = winner;
    }
    __syncthreads();

    // ---- gather (hi+lo reconstruct from packed P) + STE + loss partial ----
    float psum = 0.f;
#pragma unroll
    for (int half = 0; half < 2; ++half) {
        const int sl = (tx >> 2) + half * 64, d0 = (tx & 3) * 16;
        const int gs = S0 + sl;
        const int wi = widx[sl];
        const int gt = wi >> 4, gc = wi & 15;
        const int qq = (d0 >> 3) & 3;        // 0 or 2
        const int gf = d0 >> 5;              // 0 or 1
        const unsigned short* gh = P + ((size_t)((gt * 4 + gf) * 64) + qq * 16 + gc) * 8;
        const unsigned short* gl = P + ((size_t)((gt * 4 + 2 + gf) * 64) + qq * 16 + gc) * 8;
        bf16x8 h0 = *(const bf16x8*)(gh);          // dims d0..d0+8
        bf16x8 h1 = *(const bf16x8*)(gh + 128);    // dims d0+8..d0+16
        bf16x8 l0 = *(const bf16x8*)(gl);
        bf16x8 l1 = *(const bf16x8*)(gl + 128);
        const float* xr = xin + (size_t)gs * D + d0;
        float* oq = outq + (size_t)gs * D + d0;
#pragma unroll
        for (int g = 0; g < 4; ++g) {
            float4 xv = *(const float4*)(xr + 4 * g);
            float q0 = bf16f((unsigned short)(g < 2 ? h0[4 * g + 0] : h1[4 * g - 8 + 0])) +
                       bf16f((unsigned short)(g < 2 ? l0[4 * g + 0] : l1[4 * g - 8 + 0]));
            float q1 = bf16f((unsigned short)(g < 2 ? h0[4 * g + 1] : h1[4 * g - 8 + 1])) +
                       bf16f((unsigned short)(g < 2 ? l0[4 * g + 1] : l1[4 * g - 8 + 1]));
            float q2 = bf16f((unsigned short)(g < 2 ? h0[4 * g + 2] : h1[4 * g - 8 + 2])) +
                       bf16f((unsigned short)(g < 2 ? l0[4 * g + 2] : l1[4 * g - 8 + 2]));
            float q3 = bf16f((unsigned short)(g < 2 ? h0[4 * g + 3] : h1[4 * g - 8 + 3])) +
                       bf16f((unsigned short)(g < 2 ? l0[4 * g + 3] : l1[4 * g - 8 + 3]));
            float dx = q0 - xv.x, dy = q1 - xv.y, dz = q2 - xv.z, dw = q3 - xv.w;
            float4 o;
            o.x = xv.x + dx; o.y = xv.y + dy; o.z = xv.z + dz; o.w = xv.w + dw;
            *(float4*)(oq + 4 * g) = o;
            psum = fmaf(dx, dx, psum);
            psum = fmaf(dy, dy, psum);
            psum = fmaf(dz, dz, psum);
            psum = fmaf(dw, dw, psum);
        }
    }

    if (tx < 128)
        outidx[S0 + tx] = (float)widx[tx];

    __syncthreads();   // merge arrays dead; red aliases
    red[tx] = psum;
    __syncthreads();
    for (int st = 128; st > 0; st >>= 1) {
        if (tx < st) red[tx] += red[tx + st];
        __syncthreads();
    }
    if (tx == 0) atomicAdd(acc_g, (double)red[0]);
#undef ISSUE
#undef WAITV
#undef BODY
}

// ---------------------------------------------------------------------------
// Finalize: loss = m + 0.25*m where m = mean((q-x)^2)
// ---------------------------------------------------------------------------
__global__ void vq_finalize(const double* __restrict__ acc,
                            float* __restrict__ loss_out)
{
    float m = (float)(*acc / (double)NEL);
    *loss_out = m + 0.25f * m;
}

extern "C" void kernel_launch(void* const* d_in, const int* in_sizes, int n_in,
                              void* d_out, int out_size, void* d_ws, size_t ws_size,
                              hipStream_t stream) {
    const float* xin = (const float*)d_in[0];   // [16,64,64,64] fp32
    const float* cm  = (const float*)d_in[1];   // [64,1024] fp32

    float* out     = (float*)d_out;
    float* outq    = out;                 // 4194304 floats
    float* outidx  = out + NEL;           // 65536 floats (indices)
    float* outloss = out + NEL + NS;      // 1 float

    // workspace: packed P 256 KB | cnorm 4 KB | acc 8 B
    unsigned short* P = (unsigned short*)d_ws;
    float*  cnorm = (float*)((char*)d_ws + 262144);
    double* acc   = (double*)((char*)d_ws + 266240);

    vq_prep<<<64, 256, 0, stream>>>(cm, P, cnorm, acc);
    vq_main<<<512, 256, 0, stream>>>(xin, cm, P, cnorm, outq, outidx, acc);
    vq_finalize<<<1, 1, 0, stream>>>(acc, outloss);
}

// Round 5
// 117.387 us; speedup vs baseline: 1.0650x; 1.0490x over previous
//
#include <hip/hip_runtime.h>
#include <stdint.h>

#define NS 65536      // B*H*W samples
#define D 64          // embed dim
#define K 1024        // codebook size
#define NEL 4194304   // NS*D
#define MARGIN_KEY 0.025f  // key units (= half dist units); covers 2.7e-3 approx+pack err

typedef short bf16x8 __attribute__((ext_vector_type(8)));
typedef short s16x4 __attribute__((ext_vector_type(4)));
typedef float f32x4 __attribute__((ext_vector_type(4)));

static __device__ __forceinline__ unsigned short bf16_rne(float x) {
    union { float f; uint32_t u; } v; v.f = x;
    uint32_t r = v.u + 0x7FFFu + ((v.u >> 16) & 1u);
    return (unsigned short)(r >> 16);
}
static __device__ __forceinline__ float bf16f(unsigned short h) {
    union { uint32_t u; float f; } v; v.u = ((uint32_t)h) << 16;
    return v.f;
}

// ---------------------------------------------------------------------------
// Prep: split codebook into bf16 hi/lo, packed in MFMA-fragment order:
//   P[tile t][frag f][lane l][8 shorts]; f: 0=hi d0-31, 1=hi d32-63,
//   2=lo d0-31, 3=lo d32-63; lane = ((d&31)>>3)*16 + (k&15).
// Per-tile = 4 KB contiguous -> both global_load_lds staging and ds_read
// consumption are perfectly linear. Also ||m_k||^2 fp32 + acc zero.
// ---------------------------------------------------------------------------
__global__ __launch_bounds__(256) void vq_prep(
    const float* __restrict__ cm,        // [D,K]
    unsigned short* __restrict__ P,      // packed frags, 256 KB
    float* __restrict__ cnorm,           // [K]
    double* __restrict__ acc)
{
    const int tx = threadIdx.x;
    const int col = tx & 15;             // code within block's 16
    const int dg = tx >> 4;              // dim group 0..15 (4 dims each)
    const int b = blockIdx.x;            // == tile index t
    const int k = b * 16 + col;
    if (b == 0 && tx == 0) *acc = 0.0;

    float p = 0.f;
    s16x4 hv, lv;
#pragma unroll
    for (int j = 0; j < 4; ++j) {
        float v = cm[(dg * 4 + j) * K + k];   // 16 consecutive floats / 16 lanes
        unsigned short hb = bf16_rne(v);
        hv[j] = (short)hb;
        lv[j] = (short)bf16_rne(v - bf16f(hb));
        p = fmaf(v, v, p);
    }
    const int lane = ((dg >> 1) & 3) * 16 + col;
    const int e0 = (dg & 1) * 4;
    unsigned short* ph = P + ((size_t)(b * 4 + (dg >> 3)) * 64 + lane) * 8 + e0;
    unsigned short* pl = P + ((size_t)(b * 4 + 2 + (dg >> 3)) * 64 + lane) * 8 + e0;
    *(s16x4*)ph = hv;
    *(s16x4*)pl = lv;

    __shared__ float pn[16][17];
    pn[col][dg] = p;
    __syncthreads();
    if (tx < 16) {
        float s = 0.f;
#pragma unroll
        for (int g = 0; g < 16; ++g) s += pn[tx][g];
        cnorm[b * 16 + tx] = s;
    }
}

// ---------------------------------------------------------------------------
// Main: LDS-shared B + counted-vmcnt ring (round-4 machinery), at 4
// INDEPENDENT blocks/CU (the round-4 fix): 1024 blocks x 256 thr (4 waves),
// 64 samples/block (16/wave). LDS cut to 39.1 KB -> 4 co-resident blocks/CU
// = 16 waves/CU, each SIMD hosting ~4 waves from ~4 DIFFERENT blocks at
// different pipeline phases -> one block's barrier/ds-latency stall is
// filled by another's MFMA/VALU (round 4's lockstep left ~1500 cyc/tile
// idle with 2 lockstepped blocks/CU).
// Per tile: vmcnt(2) -> own share landed; raw s_barrier -> all waves'
// shares landed (never vmcnt(0) in-loop); issue t+3 into buf[(t-1)&3]
// (consumed-before-barrier, safe); 4x ds_read_b128 + 6 MFMA (3+3 chains)
// + packed-index top-2 (tile idx in low 6 mantissa bits, err << margin).
// x staged NEGATED: key = ||m||^2/2 - x.m directly from MFMA C-in.
// ---------------------------------------------------------------------------
__global__ __launch_bounds__(256, 4) void vq_main(
    const float* __restrict__ xin,           // [NS,D]
    const float* __restrict__ cm,            // [D,K] (exact rescore)
    const unsigned short* __restrict__ P,    // packed frags
    const float* __restrict__ cnorm,         // [K]
    float* __restrict__ outq,                // [NS,D]
    float* __restrict__ outidx,              // [NS]
    double* __restrict__ acc_g)
{
    // smemA phase1: xh[64][72] + xl[64][72] (18432 B), -x bf16 hi/lo
    // smemA phase2 (alias): skewed packed mb1/mb2 (2 x 4352 B)
    // smemA phase3 (alias): red f32[256]
    __shared__ char smemA[18432];
    __shared__ unsigned short btile[4][2048];   // 4-deep ring of 4 KB B tiles
    __shared__ float cn_lds[1024];              // ||m||^2 / 2
    __shared__ int   widx[64];

    unsigned short* xh = (unsigned short*)smemA;            // stride 72
    unsigned short* xl = (unsigned short*)(smemA + 9216);
    float* mb1 = (float*)smemA;
    float* mb2 = (float*)(smemA + 4352);
    float* red = (float*)smemA;

    const int tx = threadIdx.x;
    const int S0 = blockIdx.x * 64;
    const int w = tx >> 6, l = tx & 63;
    const int quad = l >> 4, col = l & 15;

#define ISSUE(T) do {                                                          \
        const unsigned short* g_ = P + (size_t)(T) * 2048 + tx * 8;            \
        __builtin_amdgcn_global_load_lds(g_, &btile[(T) & 3][tx * 8], 16, 0, 0); \
    } while (0)
#define WAITV(N) asm volatile("s_waitcnt vmcnt(" #N ")" ::: "memory")

    // prologue: stage tiles 0..2 (drained by the staging __syncthreads)
    ISSUE(0); ISSUE(1); ISSUE(2);

    // ---- stage -x -> bf16 hi/lo in LDS (one-time) ----
    {
        const int s = tx >> 2, d0 = (tx & 3) * 16;
        const float* gp = xin + (size_t)(S0 + s) * D + d0;
        bf16x8 hv0, hv1, lv0, lv1;
#pragma unroll
        for (int j = 0; j < 8; ++j) {
            float va = -gp[j], vb = -gp[8 + j];
            unsigned short ha = bf16_rne(va), hb = bf16_rne(vb);
            hv0[j] = (short)ha; hv1[j] = (short)hb;
            lv0[j] = (short)bf16_rne(va - bf16f(ha));
            lv1[j] = (short)bf16_rne(vb - bf16f(hb));
        }
        *(bf16x8*)(xh + s * 72 + d0)     = hv0;
        *(bf16x8*)(xh + s * 72 + d0 + 8) = hv1;
        *(bf16x8*)(xl + s * 72 + d0)     = lv0;
        *(bf16x8*)(xl + s * 72 + d0 + 8) = lv1;
#pragma unroll
        for (int q = 0; q < 4; ++q)
            cn_lds[q * 256 + tx] = 0.5f * cnorm[q * 256 + tx];
    }
    __syncthreads();   // drains x writes AND tiles 0-2 (full drain, once)

    // loop-invariant A fragments (-x): row = w*16 + col, dims quad*8 (+32)
    const int srow = w * 16 + col;
    bf16x8 AH0 = *(const bf16x8*)(xh + srow * 72 + quad * 8);
    bf16x8 AH1 = *(const bf16x8*)(xh + srow * 72 + 32 + quad * 8);
    bf16x8 AL0 = *(const bf16x8*)(xl + srow * 72 + quad * 8);
    bf16x8 AL1 = *(const bf16x8*)(xl + srow * 72 + 32 + quad * 8);

    // top-2 of key = cn/2 - x.m, tile idx packed in low 6 mantissa bits
    float b1[4], b2[4];
#pragma unroll
    for (int r = 0; r < 4; ++r) { b1[r] = 3.4e38f; b2[r] = 3.4e38f; }

#define BODY(T) do {                                                           \
        const unsigned short* bt_ = &btile[(T) & 3][0];                        \
        bf16x8 bh0 = *(const bf16x8*)(bt_ + l * 8);                            \
        bf16x8 bh1 = *(const bf16x8*)(bt_ + 512 + l * 8);                      \
        bf16x8 bl0 = *(const bf16x8*)(bt_ + 1024 + l * 8);                     \
        bf16x8 bl1 = *(const bf16x8*)(bt_ + 1536 + l * 8);                     \
        const float cnv_ = cn_lds[(T) * 16 + col];                             \
        const f32x4 cA_ = {cnv_, cnv_, cnv_, cnv_};                            \
        const f32x4 z4_ = {0.f, 0.f, 0.f, 0.f};                                \
        const unsigned tt_ = (unsigned)(T);                                    \
        f32x4 a1_ = __builtin_amdgcn_mfma_f32_16x16x32_bf16(AH0, bh0, cA_, 0, 0, 0); \
        a1_ = __builtin_amdgcn_mfma_f32_16x16x32_bf16(AH1, bh1, a1_, 0, 0, 0); \
        a1_ = __builtin_amdgcn_mfma_f32_16x16x32_bf16(AL0, bh0, a1_, 0, 0, 0); \
        f32x4 a2_ = __builtin_amdgcn_mfma_f32_16x16x32_bf16(AH0, bl0, z4_, 0, 0, 0); \
        a2_ = __builtin_amdgcn_mfma_f32_16x16x32_bf16(AH1, bl1, a2_, 0, 0, 0); \
        a2_ = __builtin_amdgcn_mfma_f32_16x16x32_bf16(AL1, bh1, a2_, 0, 0, 0); \
        _Pragma("unroll")                                                      \
        for (int r = 0; r < 4; ++r) {                                          \
            float v_ = a1_[r] + a2_[r];                                        \
            unsigned pu_ = (__builtin_bit_cast(unsigned, v_) & 0xFFFFFFC0u) | tt_; \
            float f_ = __builtin_bit_cast(float, pu_);                         \
            b2[r] = __builtin_amdgcn_fmed3f(b1[r], f_, b2[r]);                 \
            b1[r] = fminf(b1[r], f_);                                          \
        }                                                                      \
    } while (0)

    for (int t = 0; t < 61; ++t) {
        WAITV(2);                         // own share of tile t arrived
        __builtin_amdgcn_s_barrier();     // all waves' shares arrived
        ISSUE(t + 3);                     // buf[(t-1)&3]: consumed last iter
        BODY(t);
    }
    WAITV(2); __builtin_amdgcn_s_barrier(); BODY(61);
    WAITV(1); __builtin_amdgcn_s_barrier(); BODY(62);
    WAITV(0); __builtin_amdgcn_s_barrier(); BODY(63);

    // ---- merge per-lane top-2 across the 16 code-lanes (packed values) ----
    {
        const int sk = 4 * (tx + (tx >> 4));   // skew: ~2-way banks
#pragma unroll
        for (int r = 0; r < 4; ++r) {
            mb1[sk + r] = b1[r];
            mb2[sk + r] = b2[r];
        }
    }
    __syncthreads();

    if (tx < 64) {   // thread tx owns local sample tx
        const int mw = tx >> 4;              // wave that held this sample
        const int mq = (tx >> 2) & 3;        // quad = (row within 16) >> 2
        const int mr = tx & 3;               // reg
        float B1 = 3.4e38f, B2 = 3.4e38f; int I1 = 0, I2 = 0;
#pragma unroll
        for (int c = 0; c < 16; ++c) {
            const int u = mw * 64 + mq * 16 + c;
            const int e = 4 * (u + (u >> 4)) + mr;
            float v1 = mb1[e];
            float v2 = mb2[e];
            int j1 = (int)(__builtin_bit_cast(unsigned, v1) & 63u) * 16 + c;
            int j2 = (int)(__builtin_bit_cast(unsigned, v2) & 63u) * 16 + c;
            if (v1 < B1)      { B2 = B1; I2 = I1; B1 = v1; I1 = j1; }
            else if (v1 < B2) { B2 = v1; I2 = j1; }
            if (v2 < B1)      { B2 = B1; I2 = I1; B1 = v2; I1 = j2; }
            else if (v2 < B2) { B2 = v2; I2 = j2; }
        }
        int winner = I1;
        if (B2 - B1 < MARGIN_KEY) {
            // exact fp32 rescore of both candidates (key = cn/2 - dot)
            const float* xp = xin + (size_t)(S0 + tx) * D;
            float a0 = 0, a1 = 0, a2 = 0, a3 = 0, e0 = 0, e1 = 0, e2 = 0, e3 = 0;
            for (int dd = 0; dd < D; dd += 4) {
                float x0 = xp[dd], x1 = xp[dd + 1], x2 = xp[dd + 2], x3 = xp[dd + 3];
                a0 = fmaf(x0, cm[(dd + 0) * K + I1], a0);
                a1 = fmaf(x1, cm[(dd + 1) * K + I1], a1);
                a2 = fmaf(x2, cm[(dd + 2) * K + I1], a2);
                a3 = fmaf(x3, cm[(dd + 3) * K + I1], a3);
                e0 = fmaf(x0, cm[(dd + 0) * K + I2], e0);
                e1 = fmaf(x1, cm[(dd + 1) * K + I2], e1);
                e2 = fmaf(x2, cm[(dd + 2) * K + I2], e2);
                e3 = fmaf(x3, cm[(dd + 3) * K + I2], e3);
            }
            float d1 = cn_lds[I1] - ((a0 + a1) + (a2 + a3));
            float d2 = cn_lds[I2] - ((e0 + e1) + (e2 + e3));
            if (d2 < d1 || (d2 == d1 && I2 < I1)) winner = I2;
        }
        widx[tx] = winner;
    }
    __syncthreads();

    // ---- gather (hi+lo reconstruct from packed P) + STE + loss partial ----
    float psum = 0.f;
    {
        const int sl = tx >> 2, d0 = (tx & 3) * 16;
        const int gs = S0 + sl;
        const int wi = widx[sl];
        const int gt = wi >> 4, gc = wi & 15;
        const int qq = (d0 >> 3) & 3;        // 0 or 2
        const int gf = d0 >> 5;              // 0 or 1
        const unsigned short* gh = P + ((size_t)((gt * 4 + gf) * 64) + qq * 16 + gc) * 8;
        const unsigned short* gl = P + ((size_t)((gt * 4 + 2 + gf) * 64) + qq * 16 + gc) * 8;
        bf16x8 h0 = *(const bf16x8*)(gh);          // dims d0..d0+8
        bf16x8 h1 = *(const bf16x8*)(gh + 128);    // dims d0+8..d0+16
        bf16x8 l0 = *(const bf16x8*)(gl);
        bf16x8 l1 = *(const bf16x8*)(gl + 128);
        const float* xr = xin + (size_t)gs * D + d0;
        float* oq = outq + (size_t)gs * D + d0;
#pragma unroll
        for (int g = 0; g < 4; ++g) {
            float4 xv = *(const float4*)(xr + 4 * g);
            float q0 = bf16f((unsigned short)(g < 2 ? h0[4 * g + 0] : h1[4 * g - 8 + 0])) +
                       bf16f((unsigned short)(g < 2 ? l0[4 * g + 0] : l1[4 * g - 8 + 0]));
            float q1 = bf16f((unsigned short)(g < 2 ? h0[4 * g + 1] : h1[4 * g - 8 + 1])) +
                       bf16f((unsigned short)(g < 2 ? l0[4 * g + 1] : l1[4 * g - 8 + 1]));
            float q2 = bf16f((unsigned short)(g < 2 ? h0[4 * g + 2] : h1[4 * g - 8 + 2])) +
                       bf16f((unsigned short)(g < 2 ? l0[4 * g + 2] : l1[4 * g - 8 + 2]));
            float q3 = bf16f((unsigned short)(g < 2 ? h0[4 * g + 3] : h1[4 * g - 8 + 3])) +
                       bf16f((unsigned short)(g < 2 ? l0[4 * g + 3] : l1[4 * g - 8 + 3]));
            float dx = q0 - xv.x, dy = q1 - xv.y, dz = q2 - xv.z, dw = q3 - xv.w;
            float4 o;
            o.x = xv.x + dx; o.y = xv.y + dy; o.z = xv.z + dz; o.w = xv.w + dw;
            *(float4*)(oq + 4 * g) = o;
            psum = fmaf(dx, dx, psum);
            psum = fmaf(dy, dy, psum);
            psum = fmaf(dz, dz, psum);
            psum = fmaf(dw, dw, psum);
        }
    }

    if (tx < 64)
        outidx[S0 + tx] = (float)widx[tx];

    __syncthreads();   // merge arrays dead; red aliases
    red[tx] = psum;
    __syncthreads();
    for (int st = 128; st > 0; st >>= 1) {
        if (tx < st) red[tx] += red[tx + st];
        __syncthreads();
    }
    if (tx == 0) atomicAdd(acc_g, (double)red[0]);
#undef ISSUE
#undef WAITV
#undef BODY
}

// ---------------------------------------------------------------------------
// Finalize: loss = m + 0.25*m where m = mean((q-x)^2)
// ---------------------------------------------------------------------------
__global__ void vq_finalize(const double* __restrict__ acc,
                            float* __restrict__ loss_out)
{
    float m = (float)(*acc / (double)NEL);
    *loss_out = m + 0.25f * m;
}

extern "C" void kernel_launch(void* const* d_in, const int* in_sizes, int n_in,
                              void* d_out, int out_size, void* d_ws, size_t ws_size,
                              hipStream_t stream) {
    const float* xin = (const float*)d_in[0];   // [16,64,64,64] fp32
    const float* cm  = (const float*)d_in[1];   // [64,1024] fp32

    float* out     = (float*)d_out;
    float* outq    = out;                 // 4194304 floats
    float* outidx  = out + NEL;           // 65536 floats (indices)
    float* outloss = out + NEL + NS;      // 1 float

    // workspace: packed P 256 KB | cnorm 4 KB | acc 8 B
    unsigned short* P = (unsigned short*)d_ws;
    float*  cnorm = (float*)((char*)d_ws + 262144);
    double* acc   = (double*)((char*)d_ws + 266240);

    vq_prep<<<64, 256, 0, stream>>>(cm, P, cnorm, acc);
    vq_main<<<1024, 256, 0, stream>>>(xin, cm, P, cnorm, outq, outidx, acc);
    vq_finalize<<<1, 1, 0, stream>>>(acc, outloss);
}